// Round 1
// baseline (46.763 us; speedup 1.0000x reference)
//
#include <hip/hip_runtime.h>

#define M_ROWS 65536
#define LENGTH 512
#define NBLOCKS 2048
#define BLOCK 256

// One wave (64 lanes) per row; lane l covers columns [8l, 8l+8).
// Cross-lane previous element via shfl_up; column 0 contributes 0.
__global__ __launch_bounds__(BLOCK) void connect_loss_partial(
    const float* __restrict__ x,
    const float* __restrict__ mask,
    float* __restrict__ part) {
  const int wave = threadIdx.x >> 6;   // 0..3
  const int lane = threadIdx.x & 63;
  const int waves_total = gridDim.x * (BLOCK / 64);
  float acc = 0.0f;

  for (int row = blockIdx.x * (BLOCK / 64) + wave; row < M_ROWS; row += waves_total) {
    const float4* xr = reinterpret_cast<const float4*>(x + (size_t)row * LENGTH) + lane * 2;
    const float4* mr = reinterpret_cast<const float4*>(mask + (size_t)row * LENGTH) + lane * 2;
    float4 a0 = xr[0];
    float4 a1 = xr[1];
    float4 m0 = mr[0];
    float4 m1 = mr[1];

    // previous element for column 8l is column 8l-1 = lane (l-1)'s a1.w
    float prev = __shfl_up(a1.w, 1);

    float v[8] = {a0.x, a0.y, a0.z, a0.w, a1.x, a1.y, a1.z, a1.w};
    float m[8] = {m0.x, m0.y, m0.z, m0.w, m1.x, m1.y, m1.z, m1.w};

    // lane 0, column 0: diff defined as 0 (reference pads column 0 with zero)
    float p = (lane == 0) ? v[0] : prev;
#pragma unroll
    for (int c = 0; c < 8; ++c) {
      float d = v[c] - p;
      p = v[c];
      float t = fabsf(d) - 1.0f;
      acc += (t > 0.0f ? t : 0.0f) * m[c];
    }
  }

  // wave reduction (64 lanes)
#pragma unroll
  for (int off = 32; off; off >>= 1) acc += __shfl_down(acc, off);

  __shared__ float s[BLOCK / 64];
  if (lane == 0) s[wave] = acc;
  __syncthreads();
  if (threadIdx.x == 0) part[blockIdx.x] = s[0] + s[1] + s[2] + s[3];
}

__global__ __launch_bounds__(BLOCK) void connect_loss_reduce(
    const float* __restrict__ part, float* __restrict__ out, int n) {
  const int wave = threadIdx.x >> 6;
  const int lane = threadIdx.x & 63;
  float acc = 0.0f;
  for (int i = threadIdx.x; i < n; i += BLOCK) acc += part[i];
#pragma unroll
  for (int off = 32; off; off >>= 1) acc += __shfl_down(acc, off);
  __shared__ float s[BLOCK / 64];
  if (lane == 0) s[wave] = acc;
  __syncthreads();
  if (threadIdx.x == 0) out[0] = s[0] + s[1] + s[2] + s[3];
}

extern "C" void kernel_launch(void* const* d_in, const int* in_sizes, int n_in,
                              void* d_out, int out_size, void* d_ws, size_t ws_size,
                              hipStream_t stream) {
  const float* x = (const float*)d_in[0];
  const float* mask = (const float*)d_in[1];
  float* out = (float*)d_out;
  float* part = (float*)d_ws;  // NBLOCKS floats

  connect_loss_partial<<<NBLOCKS, BLOCK, 0, stream>>>(x, mask, part);
  connect_loss_reduce<<<1, BLOCK, 0, stream>>>(part, out, NBLOCKS);
}